// Round 9
// baseline (248.002 us; speedup 1.0000x reference)
//
#include <hip/hip_runtime.h>
#include <hip/hip_fp16.h>

typedef __attribute__((ext_vector_type(8))) _Float16 half8;
typedef __attribute__((ext_vector_type(2))) _Float16 h2f;
typedef __attribute__((ext_vector_type(4))) float f32x4;

#define NP 1369
#define KP 1376          /* padded row stride: 43 tiles of 32 */
#define NKT 43
#define ROWS_A 15360     /* 768 sbk * 20 t  */
#define ROWS_D 14592     /* 768 sbk * 19 dt */

/* ws layout (ushort units). total incl tsum = 84,036,608 B <= 84.25MB proven */
#define PA_OFF   0
#define PD_OFF   (ROWS_A * KP)
#define PWH_OFF  (PD_OFF + ROWS_D * KP)
#define PWD_OFF  (PWH_OFF + NKT * 16 * 512)
#define PW2_OFF  (PWD_OFF + NKT * 16 * 512)
#define PWD2_OFF (PW2_OFF + 8 * 16 * 512)
#define TSUM_OFF (PWD2_OFF + 8 * 8 * 512)   /* 768 floats follow */

__device__ __forceinline__ unsigned short f2h(float f) {
    __half h = __float2half(f);
    return __half_as_ushort(h);
}
__device__ __forceinline__ h2f u2h2(unsigned int u) {
    h2f r; __builtin_memcpy(&r, &u, 4); return r;
}
__device__ __forceinline__ unsigned h2u(h2f h) {
    unsigned r; __builtin_memcpy(&r, &h, 4); return r;
}

// ============ k0: pack weights into MFMA-B fragment layout (fp16) ============
__global__ __launch_bounds__(256)
void k0_pack(const float* __restrict__ w_h1, const float* __restrict__ wd1,
             const float* __restrict__ wm1,  const float* __restrict__ ws1,
             const float* __restrict__ wd2,  unsigned short* __restrict__ wsu)
{
    int idx = blockIdx.x * 256 + threadIdx.x;      // 0..802815
    int local, mode;
    unsigned short* dst;
    if (idx < 352256)      { mode = 0; local = idx;          dst = wsu + PWH_OFF; }
    else if (idx < 704512) { mode = 1; local = idx - 352256; dst = wsu + PWD_OFF; }
    else if (idx < 770048) { mode = 2; local = idx - 704512; dst = wsu + PW2_OFF; }
    else                   { mode = 3; local = idx - 770048; dst = wsu + PWD2_OFF; }
    int j = local & 7, lane = (local >> 3) & 63, rest = local >> 9;
    int NTn = (mode == 3) ? 8 : 16;
    int nt = rest % NTn, kt = rest / NTn;
    int k = kt * 32 + ((lane >> 4) << 3) + j;
    int n = nt * 16 + (lane & 15);
    float v = 0.f;
    if (mode == 0)      { if (k < NP) v = w_h1[k * 256 + n]; }
    else if (mode == 1) { if (k < NP) v = wd1[k * 256 + n]; }
    else if (mode == 2) { v = (n < 128) ? wm1[k * 128 + n] : ws1[k * 128 + (n - 128)]; }
    else                { v = wd2[k * 128 + n]; }
    dst[local] = f2h(v);
}

// ============ k0b: per-template sum -> baseline C = 0.5 * sum(T) ============
__global__ __launch_bounds__(64)
void k0b_tsum(const float* __restrict__ digit, float* __restrict__ tsum)
{
    const int sbk = blockIdx.x, l = threadIdx.x;
    const float* tp = digit + (size_t)sbk * 784;
    float s = 0.f;
    for (int i = l; i < 784; i += 64) s += tp[i];
    for (int o = 32; o; o >>= 1) s += __shfl_xor(s, o, 64);
    if (l == 0) tsum[sbk] = 0.5f * s;
}

// ============ k1a: correlation as im2col MFMA GEMM (dual-copy frame) ============
// grid 960 = (b 16) x (t 20) x (ntile 3); block 256 (4 waves).
__global__ __launch_bounds__(256, 4)
void k1a_corr(const float* __restrict__ frames, const float* __restrict__ digit,
              const float* __restrict__ tsum, unsigned short* __restrict__ wsu)
{
    __shared__ __align__(16) unsigned short Bs[28 * 512];      // 28,672 B
    __shared__ __align__(16) unsigned int frboth[2][64 * 36];  // 18,432 B: aligned + shifted
    __shared__ float Cn[16];

    const int tid = threadIdx.x, l = tid & 63, w = tid >> 6;
    const int nt = blockIdx.x % 3;
    const int t  = (blockIdx.x / 3) % 20;
    const int bb = blockIdx.x / 60;
    const int N0 = nt * 16;

    // ---- stage B fragments: slot = kt*64 + lane ----
    for (int slot = tid; slot < 1792; slot += 256) {
        int kt = slot >> 6, sl = slot & 63;
        int n  = N0 + (sl & 15);
        int v0 = (sl >> 4) << 3;
        int sbk_n = ((n / 3) * 16 + bb) * 3 + (n % 3);
        const float* tp = digit + (size_t)sbk_n * 784 + kt * 28 + v0;
        float4 fa = *(const float4*)tp;
        float4 fb = (v0 <= 16) ? *(const float4*)(tp + 4) : make_float4(0.f, 0.f, 0.f, 0.f);
        uint4 pk;
        pk.x = (unsigned)f2h(fa.x) | ((unsigned)f2h(fa.y) << 16);
        pk.y = (unsigned)f2h(fa.z) | ((unsigned)f2h(fa.w) << 16);
        pk.z = (unsigned)f2h(fb.x) | ((unsigned)f2h(fb.y) << 16);
        pk.w = (unsigned)f2h(fb.z) | ((unsigned)f2h(fb.w) << 16);
        *(uint4*)(Bs + slot * 8) = pk;
    }
    if (tid < 16) {
        int n = N0 + tid;
        int sbk_n = ((n / 3) * 16 + bb) * 3 + (n % 3);
        Cn[tid] = tsum[sbk_n];
    }
    // ---- stage frame copy 0 (aligned fp16 pairs); zero col-pads dwords 32..35 ----
    frboth[0][(tid >> 2) * 36 + 32 + (tid & 3)] = 0u;
    {
        const float4* fp4 = (const float4*)(frames + (size_t)(bb * 20 + t) * 4096);
        for (int idx = tid; idx < 1024; idx += 256) {
            float4 v = fp4[idx];
            int r = idx >> 4, c4 = idx & 15;
            unsigned lo = (unsigned)f2h(v.x) | ((unsigned)f2h(v.y) << 16);
            unsigned hi = (unsigned)f2h(v.z) | ((unsigned)f2h(v.w) << 16);
            *(uint2*)&frboth[0][r * 36 + c4 * 2] = make_uint2(lo, hi);
        }
    }
    __syncthreads();
    // ---- build shifted copy: frs[r][d] = halfs (2d+1, 2d+2) ----
    for (int i = tid; i < 64 * 34; i += 256) {
        int r = i / 34, d = i - r * 34;
        unsigned lo = frboth[0][r * 36 + d], hi = frboth[0][r * 36 + d + 1];
        frboth[1][r * 36 + d] = (lo >> 16) | (hi << 16);
    }
    __syncthreads();

    const int c15 = l & 15, quad = l >> 4, v0q = quad << 3;
    const int cntw = (89 - w) / 4;        // 22,22,21,21 tiles per wave

    for (int m0 = 0; m0 < cntw; m0 += 8) {
        const int tc = (cntw - m0 < 8) ? (cntw - m0) : 8;
        int addrb[8];
#pragma unroll
        for (int it = 0; it < 8; ++it) {
            int tI = w + 4 * (m0 + it);
            int p  = tI * 16 + c15;
            int pc = p > 1368 ? 1368 : p;
            int i  = pc / 37;
            int jj = pc - i * 37;
            int c  = jj + v0q;
            addrb[it] = (c & 1) * 9216 + i * 144 + ((c >> 1) << 2);
        }
        f32x4 acc[8];
#pragma unroll
        for (int it = 0; it < 8; ++it) acc[it] = (f32x4){0.f, 0.f, 0.f, 0.f};

        for (int kt = 0; kt < 28; ++kt) {
            half8 bf = *(const half8*)(Bs + kt * 512 + l * 8);
            const char* fb = (const char*)frboth + (size_t)kt * 144;
#pragma unroll
            for (int it = 0; it < 8; ++it) {
                if (it < tc) {
                    const char* ap = fb + addrb[it];
                    union { unsigned u[4]; half8 h8; } af;
                    af.u[0] = *(const unsigned*)(ap);
                    af.u[1] = *(const unsigned*)(ap + 4);
                    af.u[2] = *(const unsigned*)(ap + 8);
                    af.u[3] = *(const unsigned*)(ap + 12);
                    acc[it] = __builtin_amdgcn_mfma_f32_16x16x32_f16(af.h8, bf, acc[it], 0, 0, 0);
                }
            }
        }
        // ---- epilogue: conv - C -> fp16 into PA ----
        const float C = Cn[c15];
        const int n = N0 + c15;
        const int sbk_n = ((n / 3) * 16 + bb) * 3 + (n % 3);
        unsigned short* orow = wsu + PA_OFF + (size_t)(sbk_n * 20 + t) * KP;
#pragma unroll
        for (int it = 0; it < 8; ++it) {
            if (it < tc) {
                int tI = w + 4 * (m0 + it);
                int p0 = tI * 16 + quad * 4;
                if (p0 + 3 <= 1368) {
                    ushort4 st;
                    st.x = f2h(acc[it][0] - C); st.y = f2h(acc[it][1] - C);
                    st.z = f2h(acc[it][2] - C); st.w = f2h(acc[it][3] - C);
                    *(ushort4*)(orow + p0) = st;
                } else {
#pragma unroll
                    for (int r = 0; r < 4; ++r)
                        if (p0 + r <= 1368) orow[p0 + r] = f2h(acc[it][r] - C);
                }
            }
        }
    }
}

// ============ k1b: per-sbk diff -> PD and in-place softmax -> PA ============
__global__ __launch_bounds__(256)
void k1b_sm(unsigned short* __restrict__ wsu)
{
    __shared__ __align__(16) unsigned short rows[20 * KP];
    const int tid = threadIdx.x, l = tid & 63, w = tid >> 6;
    const int sbk = blockIdx.x;
    unsigned short* pa = wsu + PA_OFF + (size_t)sbk * 20 * KP;
    unsigned short* pd = wsu + PD_OFF + (size_t)sbk * 19 * KP;

    for (int i = tid; i < 20 * 172; i += 256) {
        int r = i / 172, q = i - r * 172;
        *(uint4*)(rows + r * KP + q * 8) = *(const uint4*)(pa + (size_t)r * KP + q * 8);
    }
    __syncthreads();

    for (int i = tid; i < 19 * 172; i += 256) {
        int d = i / 172, q = i - d * 172;
        const unsigned* c1 = (const unsigned*)(rows + (d + 1) * KP + q * 8);
        const unsigned* c0 = (const unsigned*)(rows + d * KP + q * 8);
        uint4 st;
        st.x = h2u(u2h2(c1[0]) - u2h2(c0[0]));
        st.y = h2u(u2h2(c1[1]) - u2h2(c0[1]));
        st.z = h2u(u2h2(c1[2]) - u2h2(c0[2]));
        st.w = h2u(u2h2(c1[3]) - u2h2(c0[3]));
        *(uint4*)(pd + (size_t)d * KP + q * 8) = st;
    }

    for (int r = w; r < 20; r += 4) {
        const unsigned* rp = (const unsigned*)(rows + r * KP);
        float mx = -3.0e38f;
        for (int q = l; q < 685; q += 64) {
            unsigned v = rp[q];
            h2f h = u2h2(v);
            float f0 = (float)h[0], f1 = (float)h[1];
            if (q == 684) f1 = -3.0e38f;
            mx = fmaxf(mx, fmaxf(f0, f1));
        }
        for (int o = 32; o; o >>= 1) mx = fmaxf(mx, __shfl_xor(mx, o, 64));
        float sum = 0.f;
        for (int q = l; q < 685; q += 64) {
            unsigned v = rp[q];
            h2f h = u2h2(v);
            float e0 = __expf((float)h[0] - mx);
            float e1 = (q == 684) ? 0.f : __expf((float)h[1] - mx);
            sum += e0 + e1;
        }
        for (int o = 32; o; o >>= 1) sum += __shfl_xor(sum, o, 64);
        const float inv = 1.0f / sum;
        unsigned* prow = (unsigned*)(pa + (size_t)r * KP);
        for (int q = l; q < 685; q += 64) {
            unsigned v = rp[q];
            h2f h = u2h2(v);
            float e0 = __expf((float)h[0] - mx) * inv;
            float e1 = (q == 684) ? 0.f : __expf((float)h[1] - mx) * inv;
            prow[q] = (unsigned)f2h(e0) | ((unsigned)f2h(e1) << 16);
        }
    }
}

// ============ k2_gemm1: LDS-free, barrier-free. grid 468 (240 A + 228 B), M=64 ============
__global__ __launch_bounds__(256)
void k2_gemm1(unsigned short* __restrict__ wsu,
              const float* __restrict__ b_h1, const float* __restrict__ bd1)
{
    const int tid = threadIdx.x, l = tid & 63, w = tid >> 6;
    const int c15 = l & 15, quad = l >> 4;
    const bool pA = blockIdx.x < 240;
    const int M0 = (pA ? blockIdx.x : blockIdx.x - 240) * 64;
    unsigned short* Abase = wsu + (pA ? PA_OFF : PD_OFF);
    const unsigned short* PW = wsu + (pA ? PWH_OFF : PWD_OFF);
    const float* bias = pA ? b_h1 : bd1;

    f32x4 acc[16];
#pragma unroll
    for (int n = 0; n < 16; ++n) acc[n] = (f32x4){0.f, 0.f, 0.f, 0.f};

    const unsigned short* arow = Abase + (size_t)(M0 + w * 16 + c15) * KP + quad * 8;

    for (int kt = 0; kt < NKT; ++kt) {
        half8 af = *(const half8*)(arow + kt * 32);
        const unsigned short* bkt = PW + (size_t)kt * 8192 + l * 8;
#pragma unroll
        for (int nt = 0; nt < 16; ++nt) {
            half8 bf = *(const half8*)(bkt + nt * 512);
            acc[nt] = __builtin_amdgcn_mfma_f32_16x16x32_f16(af, bf, acc[nt], 0, 0, 0);
        }
    }
#pragma unroll
    for (int nt = 0; nt < 16; ++nt) {
        const int col = nt * 16 + c15;
        const float bv = bias[col];
#pragma unroll
        for (int r = 0; r < 4; ++r) {
            const int row = M0 + w * 16 + quad * 4 + r;
            float v = acc[nt][r] + bv;
            v = v > 0.f ? v : 0.f;
            Abase[(size_t)row * KP + col] = f2h(v);
        }
    }
}

// ============ k2_heads: LDS-free, M=64 tiles. grids 240 / 228 ============
template <bool PATHA>
__global__ __launch_bounds__(256)
void k2_heads(unsigned short* __restrict__ wsu,
              const float* __restrict__ b1a, const float* __restrict__ b1b,
              const float* __restrict__ w2a, const float* __restrict__ b2a,
              const float* __restrict__ w2b, const float* __restrict__ b2b,
              float* __restrict__ out)
{
    constexpr int NT2 = PATHA ? 16 : 8;
    const int tid = threadIdx.x, l = tid & 63, w = tid >> 6;
    const int c = l & 15, quad = l >> 4;
    const int M0 = blockIdx.x * 64;
    unsigned short* Abase = wsu + (PATHA ? PA_OFF : PD_OFF);
    const unsigned short* PW = wsu + (PATHA ? PW2_OFF : PWD2_OFF);

    f32x4 acc[NT2];
#pragma unroll
    for (int n = 0; n < NT2; ++n) acc[n] = (f32x4){0.f, 0.f, 0.f, 0.f};

    const unsigned short* arow = Abase + (size_t)(M0 + w * 16 + c) * KP + quad * 8;

    for (int kt = 0; kt < 8; ++kt) {
        half8 af = *(const half8*)(arow + kt * 32);
        const unsigned short* bkt = PW + (size_t)kt * (NT2 * 512) + l * 8;
#pragma unroll
        for (int nt = 0; nt < NT2; ++nt) {
            half8 bf = *(const half8*)(bkt + nt * 512);
            acc[nt] = __builtin_amdgcn_mfma_f32_16x16x32_f16(af, bf, acc[nt], 0, 0, 0);
        }
    }
#pragma unroll
    for (int nt = 0; nt < NT2; ++nt) {
        float bv;
        if (PATHA) bv = (nt < 8) ? b1a[nt * 16 + c] : b1b[(nt - 8) * 16 + c];
        else       bv = b1a[nt * 16 + c];
#pragma unroll
        for (int r = 0; r < 4; ++r) {
            float v = acc[nt][r] + bv;
            acc[nt][r] = v > 0.f ? v : 0.f;
        }
    }
    float pm[2][4], ps[2][4];
#pragma unroll
    for (int d = 0; d < 2; ++d)
#pragma unroll
        for (int r = 0; r < 4; ++r) { pm[d][r] = 0.f; ps[d][r] = 0.f; }
#pragma unroll
    for (int d = 0; d < 2; ++d)
#pragma unroll
        for (int nt = 0; nt < 8; ++nt) {
            const float wmv = w2a[(nt * 16 + c) * 2 + d];
            float wsv = 0.f;
            if (PATHA) wsv = w2b[(nt * 16 + c) * 2 + d];
#pragma unroll
            for (int r = 0; r < 4; ++r) {
                pm[d][r] = fmaf(acc[nt][r], wmv, pm[d][r]);
                if (PATHA) ps[d][r] = fmaf(acc[nt + 8][r], wsv, ps[d][r]);
            }
        }
#pragma unroll
    for (int o = 1; o < 16; o <<= 1)
#pragma unroll
        for (int d = 0; d < 2; ++d)
#pragma unroll
            for (int r = 0; r < 4; ++r) {
                pm[d][r] += __shfl_xor(pm[d][r], o, 64);
                if (PATHA) ps[d][r] += __shfl_xor(ps[d][r], o, 64);
            }
    if (c == 0) {
#pragma unroll
        for (int r = 0; r < 4; ++r) {
            const int row = M0 + w * 16 + quad * 4 + r;
            if (PATHA) {
                const int sbk = row / 20, t = row % 20;
                const int sb = sbk / 3, kk = sbk % 3;
                const int oi = ((sb * 20 + t) * 3 + kk) * 2;
                out[oi + 0] = tanhf(pm[0][r] + b2a[0]);
                out[oi + 1] = tanhf(pm[1][r] + b2a[1]);
                out[30720 + oi + 0] = __expf(ps[0][r] + b2b[0]);
                out[30720 + oi + 1] = __expf(ps[1][r] + b2b[1]);
            } else {
                const int sbk = row / 19, dt = row % 19;
                const int sb = sbk / 3, kk = sbk % 3;
                const int oi = 61440 + ((sb * 19 + dt) * 3 + kk) * 2;
                out[oi + 0] = tanhf(pm[0][r] + b2a[0]);
                out[oi + 1] = tanhf(pm[1][r] + b2a[1]);
            }
        }
    }
}

extern "C" void kernel_launch(void* const* d_in, const int* in_sizes, int n_in,
                              void* d_out, int out_size, void* d_ws, size_t ws_size,
                              hipStream_t stream) {
    const float* frames = (const float*)d_in[0];
    const float* digit  = (const float*)d_in[1];
    const float* w_h1   = (const float*)d_in[2];
    const float* b_h1   = (const float*)d_in[3];
    const float* wm1    = (const float*)d_in[4];
    const float* bm1    = (const float*)d_in[5];
    const float* wm2    = (const float*)d_in[6];
    const float* bm2    = (const float*)d_in[7];
    const float* ws1    = (const float*)d_in[8];
    const float* bs1    = (const float*)d_in[9];
    const float* ws2    = (const float*)d_in[10];
    const float* bs2    = (const float*)d_in[11];
    const float* wd1    = (const float*)d_in[12];
    const float* bd1    = (const float*)d_in[13];
    const float* wd2    = (const float*)d_in[14];
    const float* bd2    = (const float*)d_in[15];
    const float* wd3    = (const float*)d_in[16];
    const float* bd3    = (const float*)d_in[17];

    unsigned short* wsu = (unsigned short*)d_ws;
    float* tsum = (float*)(wsu + TSUM_OFF);
    float* o = (float*)d_out;

    k0_pack<<<dim3(3136), dim3(256), 0, stream>>>(w_h1, wd1, wm1, ws1, wd2, wsu);
    k0b_tsum<<<dim3(768), dim3(64), 0, stream>>>(digit, tsum);
    k1a_corr<<<dim3(960), dim3(256), 0, stream>>>(frames, digit, tsum, wsu);
    k1b_sm<<<dim3(768), dim3(256), 0, stream>>>(wsu);
    k2_gemm1<<<dim3(468), dim3(256), 0, stream>>>(wsu, b_h1, bd1);
    k2_heads<true><<<dim3(240), dim3(256), 0, stream>>>(wsu, bm1, bs1, wm2, bm2, ws2, bs2, o);
    k2_heads<false><<<dim3(228), dim3(256), 0, stream>>>(wsu, bd2, nullptr, wd3, bd3, nullptr, nullptr, o);
}